// Round 1
// 158.902 us; speedup vs baseline: 1.0009x; 1.0009x over previous
//
#include <hip/hip_runtime.h>

// B=32, N=2048, FE=32, T=12, OUT=3
#define FE_ 32
#define T_  12
#define M_  (32 * 2048)
#define LANES_PER_SEQ 4            // lanes p=0..2 load float4 t-slices; lane 3 duplicates
#define SEQ_PER_BLOCK 64
#define THREADS (SEQ_PER_BLOCK * LANES_PER_SEQ)   // 256 = 4 waves, no LDS, no barrier

// Lane (s, q): q<3 computes gates for t in [4q, 4q+4) via one float4 load per
// feature (16B/lane, 16B-aligned: seq stride = 1536B, f stride = 48B).
// Gates move to the recurrence with width-4 __shfl (no LDS round-trip, no
// __syncthreads). All 4 lanes redundantly run the 12-step recurrence; lane q
// computes and stores only out[m*3+q].
__global__ __launch_bounds__(THREADS) void gru_fused_kernel(
    const float* __restrict__ x,      // (M, FE, T)
    const float* __restrict__ w_ih,   // (3, FE)
    const float* __restrict__ w_hh,   // (3, 1)
    const float* __restrict__ b_ih,   // (3,)
    const float* __restrict__ b_hh,   // (3,)
    const float* __restrict__ lin_w,  // (3, T)
    const float* __restrict__ lin_b,  // (3,)
    float* __restrict__ out)          // (M, 3)
{
    const int tid = threadIdx.x;
    const int q   = tid & 3;                  // lane within 4-lane seq group
    const int s   = tid >> 2;                 // sequence within block
    const int m   = blockIdx.x * SEQ_PER_BLOCK + s;
    const int p   = (q < 3) ? q : 2;          // load slot; lane 3 duplicates slot 2

    // ---- phase 1: gates for t in [4p, 4p+4), 3 gates x 4 t-cols per lane ----
    const float4* __restrict__ xp =
        reinterpret_cast<const float4*>(x + (size_t)m * (FE_ * T_)) + p;

    const float bi0 = b_ih[0], bi1 = b_ih[1], bi2 = b_ih[2];
    float a0[4], a1[4], a2[4];
#pragma unroll
    for (int j = 0; j < 4; ++j) { a0[j] = bi0; a1[j] = bi1; a2[j] = bi2; }

#pragma unroll
    for (int f = 0; f < FE_; ++f) {
        const float4 xv = xp[f * 3];                  // x[m, f, 4p..4p+3]
        const float w0 = w_ih[0 * FE_ + f];           // wave-uniform scalar loads
        const float w1 = w_ih[1 * FE_ + f];
        const float w2 = w_ih[2 * FE_ + f];
        a0[0] = fmaf(xv.x, w0, a0[0]);
        a0[1] = fmaf(xv.y, w0, a0[1]);
        a0[2] = fmaf(xv.z, w0, a0[2]);
        a0[3] = fmaf(xv.w, w0, a0[3]);
        a1[0] = fmaf(xv.x, w1, a1[0]);
        a1[1] = fmaf(xv.y, w1, a1[1]);
        a1[2] = fmaf(xv.z, w1, a1[2]);
        a1[3] = fmaf(xv.w, w1, a1[3]);
        a2[0] = fmaf(xv.x, w2, a2[0]);
        a2[1] = fmaf(xv.y, w2, a2[1]);
        a2[2] = fmaf(xv.z, w2, a2[2]);
        a2[3] = fmaf(xv.w, w2, a2[3]);
    }

    // ---- phase 2: recurrence + per-lane output tap (all shuffle indices
    //      become compile-time constants after full unroll) ----
    const float wh0 = w_hh[0], wh1 = w_hh[1], wh2 = w_hh[2];
    const float bh0 = b_hh[0], bh1 = b_hh[1], bh2 = b_hh[2];

    const int qe = (q < 3) ? q : 2;           // lane 3 mirrors lane 2 (no store)
    const float4* __restrict__ lw4 =
        reinterpret_cast<const float4*>(lin_w + qe * T_);   // 48B offset: 16B-aligned
    const float4 lwa = lw4[0], lwb = lw4[1], lwc = lw4[2];
    const float lw[12] = { lwa.x, lwa.y, lwa.z, lwa.w,
                           lwb.x, lwb.y, lwb.z, lwb.w,
                           lwc.x, lwc.y, lwc.z, lwc.w };

    float oq = lin_b[qe];
    float h  = 0.0f;
#pragma unroll
    for (int tt = 0; tt < T_; ++tt) {
        const int d  = tt >> 2;               // source lane in group (0..2)
        const int j  = tt & 3;                // register slot (0..3)
        const float g0 = __shfl(a0[j], d, LANES_PER_SEQ);
        const float g1 = __shfl(a1[j], d, LANES_PER_SEQ);
        const float g2 = __shfl(a2[j], d, LANES_PER_SEQ);

        const float r = 1.0f / (1.0f + __expf(-(g0 + wh0 * h + bh0)));
        const float z = 1.0f / (1.0f + __expf(-(g1 + wh1 * h + bh1)));
        const float y = g2 + r * (wh2 * h + bh2);
        const float n = 1.0f - 2.0f / (1.0f + __expf(2.0f * y));  // tanh(y)
        h = (1.0f - z) * n + z * h;

        const float ht = h > 0.0f ? h : 0.0f;                     // relu
        oq = fmaf(ht, lw[tt], oq);
    }

    if (q < 3) out[(size_t)m * 3 + q] = oq;   // 48 lanes/wave, contiguous 12B/seq
}

extern "C" void kernel_launch(void* const* d_in, const int* in_sizes, int n_in,
                              void* d_out, int out_size, void* d_ws, size_t ws_size,
                              hipStream_t stream) {
    (void)in_sizes; (void)n_in; (void)d_ws; (void)ws_size; (void)out_size;
    const float* x     = (const float*)d_in[0];
    const float* w_ih  = (const float*)d_in[1];
    const float* w_hh  = (const float*)d_in[2];
    const float* b_ih  = (const float*)d_in[3];
    const float* b_hh  = (const float*)d_in[4];
    const float* lin_w = (const float*)d_in[5];
    const float* lin_b = (const float*)d_in[6];
    float* out = (float*)d_out;

    const int grid = M_ / SEQ_PER_BLOCK;   // 1024 blocks x 256 threads (4 waves)
    gru_fused_kernel<<<grid, THREADS, 0, stream>>>(x, w_ih, w_hh, b_ih, b_hh,
                                                   lin_w, lin_b, out);
}